// Round 6
// baseline (235.172 us; speedup 1.0000x reference)
//
#include <hip/hip_runtime.h>

// ---------------------------------------------------------------------------
// SelfMultiheadAttn fwd: T=2048, B=4, E=1024, H=16, D=64, causal.
// Round 14: gemm256 ported to the 8-phase counted-vmcnt schedule (T2+T3+T4+T5):
//   256x256 tile, BK=64, 8 waves (512 thr), LDS 128KB = 2buf x 2half x {A,B}.
//   A-rows per wave SPLIT (m = (w&1)*64 + (mi>>2)*128 + (mi&3)*16) so A-half0
//   frees after ph2 -> stage slots; B wave-contiguous (one head/wave keeps the
//   V-transpose epilogue). Stage slots/waits (per-wave FIFO-verified):
//   ph1:A1(t+1)+vm4, ph2:B0(t+1), ph3:B1(t+1)+vm12, ph4:A0(t+2),
//   ph5:A1(t+2)+vm4, ph6:B0(t+2), ph7:B1(t+2)+vm12, ph8:A0(t+3);
//   last iter: ph5 vm0, ph7 vm4. b-frags register-held per tile (24 ds_read
//   per 64 MFMA). lgkmcnt(0) before each trailing barrier closes the
//   read-vs-DMA WAR. Grid (12,32)=384 blocks, 1 block/CU.
// Round-5 counters: gemm256 was 78.4us @ 26% MfmaUtil = the m97 2-barrier
// ceiling; attn (8-wave) dropped out of top-5.
// Kept: attn round-13 (8-wave, counted vmcnt, XCD-paired grid), gemm128,
// merged cvt, exp2-folded W_q.
// ---------------------------------------------------------------------------

typedef float  f32x4  __attribute__((ext_vector_type(4)));
typedef short  s16x8  __attribute__((ext_vector_type(8)));
typedef __bf16 bf16x8 __attribute__((ext_vector_type(8)));

#define T_DIM 2048
#define B_DIM 4
#define E_DIM 1024
#define PLANE (T_DIM * 64)   // elements per (which,b,h) plane

#define VMC(N) asm volatile("s_waitcnt vmcnt(" #N ")" ::: "memory")
#define LGKM0() asm volatile("s_waitcnt lgkmcnt(0)" ::: "memory")
#define BAR() __builtin_amdgcn_s_barrier()

__device__ inline unsigned short f2bf(float f) {
  return (unsigned short)((__builtin_bit_cast(unsigned int, f) + 0x8000u) >> 16);
}

__device__ inline f32x4 mfma16(s16x8 a, s16x8 b, f32x4 c) {
  return __builtin_amdgcn_mfma_f32_16x16x32_bf16(
      __builtin_bit_cast(bf16x8, a), __builtin_bit_cast(bf16x8, b), c, 0, 0, 0);
}

__device__ inline void gl2lds16(const unsigned short* g, unsigned short* l) {
  __builtin_amdgcn_global_load_lds(
      (__attribute__((address_space(1))) unsigned int*)g,
      (__attribute__((address_space(3))) unsigned int*)l, 16, 0, 0);
}

// pack hi16(a) | hi16(b)<<16  (bf16 truncation) in one v_perm
__device__ inline unsigned packbf(float a, float b) {
  return __builtin_amdgcn_perm(__builtin_bit_cast(unsigned, b),
                               __builtin_bit_cast(unsigned, a), 0x07060302u);
}

// ---------------------------------------------------------------------------
// Merged input conversion: blocks [0,8192) query -> xb; [8192,11264) W_in ->
// winb (first E*E/4 float4s carry the Q scale); [11264,12288) W_out -> wob
// (skipped when do_wout==0; fallback path converts W_out after attn).
// ---------------------------------------------------------------------------
__global__ __launch_bounds__(256)
void cvt_all(const float* __restrict__ q, const float* __restrict__ wi,
             const float* __restrict__ wo, unsigned short* __restrict__ xb,
             unsigned short* __restrict__ wib, unsigned short* __restrict__ wob,
             float qs, int do_wout) {
  int blk = blockIdx.x;
  const float* src;
  unsigned short* dst;
  int i;
  float sc = 1.0f;
  if (blk < 8192) {
    src = q; dst = xb; i = blk * 256 + threadIdx.x;
  } else if (blk < 11264) {
    src = wi; dst = wib; i = (blk - 8192) * 256 + threadIdx.x;
    if (i < (E_DIM * E_DIM / 4)) sc = qs;
  } else {
    if (!do_wout) return;
    src = wo; dst = wob; i = (blk - 11264) * 256 + threadIdx.x;
  }
  float4 v = ((const float4*)src)[i];
  ushort4 o;
  o.x = f2bf(v.x * sc); o.y = f2bf(v.y * sc);
  o.z = f2bf(v.z * sc); o.w = f2bf(v.w * sc);
  ((ushort4*)dst)[i] = o;
}

__global__ __launch_bounds__(256)
void cvt_bf16(const float* __restrict__ in, unsigned short* __restrict__ out,
              int n4) {
  int i = blockIdx.x * 256 + threadIdx.x;
  if (i >= n4) return;
  float4 v = ((const float4*)in)[i];
  ushort4 o;
  o.x = f2bf(v.x); o.y = f2bf(v.y); o.z = f2bf(v.z); o.w = f2bf(v.w);
  ((ushort4*)out)[i] = o;
}

// ---------------------------------------------------------------------------
// gemm256: C[m,n]=sum_k A[m,k]*B[n,k]; 256x256 tile, 8-phase counted-vmcnt
// schedule. Epilogue -> qkv scatter; V block via per-wave LDS transpose.
// ---------------------------------------------------------------------------
__global__ __launch_bounds__(512, 2)
void gemm256(const unsigned short* __restrict__ A,
             const unsigned short* __restrict__ Bw,
             unsigned short* __restrict__ Cq, int K) {
  // [buf][half][128 rows x 64 cols] each; A + B = 128 KB total
  __shared__ __attribute__((aligned(16))) unsigned short As[2][2][8192];
  __shared__ __attribute__((aligned(16))) unsigned short Bs[2][2][8192];

  const int tid = threadIdx.x, lane = tid & 63, w = tid >> 6;  // w 0..7
  const int row16 = lane & 15, quad = lane >> 4;
  const int m0 = blockIdx.y * 256, n0 = blockIdx.x * 256;
  const int r8 = lane >> 3;
  const int jsw = (lane & 7) ^ r8;   // staging source swizzle
  const int sw7 = row16 & 7;         // read-side swizzle key

  f32x4 acc[8][4];
#pragma unroll
  for (int i = 0; i < 8; ++i)
#pragma unroll
    for (int j = 0; j < 4; ++j) acc[i][j] = (f32x4){0.f, 0.f, 0.f, 0.f};

  auto stageA = [&](int tile, int half) {
#pragma unroll
    for (int i2 = 0; i2 < 2; ++i2) {
      int ia = w * 2 + i2;  // 0..15
      gl2lds16(A + (size_t)(m0 + half * 128 + ia * 8 + r8) * K + tile * 64 +
                   jsw * 8,
               &As[tile & 1][half][ia * 512]);
    }
  };
  auto stageB = [&](int tile, int half) {
#pragma unroll
    for (int i2 = 0; i2 < 2; ++i2) {
      int ia = w * 2 + i2;
      gl2lds16(Bw + (size_t)(n0 + half * 128 + ia * 8 + r8) * K + tile * 64 +
                    jsw * 8,
               &Bs[tile & 1][half][ia * 512]);
    }
  };

  s16x8 a[4][2], bq[4][2];

  auto lda = [&](int buf, int mlo) {  // mlo literal at call sites (0 or 4)
#pragma unroll
    for (int mi2 = 0; mi2 < 4; ++mi2)
#pragma unroll
      for (int s = 0; s < 2; ++s)
        a[mi2][s] = *(const s16x8*)&As[buf][mlo >> 2]
            [((w & 1) * 64 + mi2 * 16 + row16) * 64 +
             (((s * 4 + quad) ^ sw7) * 8)];
  };
  auto ldb = [&](int buf) {  // all 4 n-frags, both ksubs, register-held
#pragma unroll
    for (int ni = 0; ni < 4; ++ni)
#pragma unroll
      for (int s = 0; s < 2; ++s)
        bq[ni][s] = *(const s16x8*)&Bs[buf][w >> 2]
            [(((w >> 1) & 1) * 64 + ni * 16 + row16) * 64 +
             (((s * 4 + quad) ^ sw7) * 8)];
  };
  auto mm = [&](int mlo, int nlo) {  // 16 MFMA
    __builtin_amdgcn_s_setprio(1);
#pragma unroll
    for (int mi2 = 0; mi2 < 4; ++mi2)
#pragma unroll
      for (int ni2 = 0; ni2 < 2; ++ni2)
#pragma unroll
        for (int s = 0; s < 2; ++s)
          acc[mlo + mi2][nlo + ni2] =
              mfma16(a[mi2][s], bq[nlo + ni2][s], acc[mlo + mi2][nlo + ni2]);
    __builtin_amdgcn_s_setprio(0);
  };

  const int NJ = K / 128;  // 8 iters of 2 K-tiles

  // prologue = virtual iter -1, slots ph4-8
  stageA(0, 0); stageA(0, 1); stageB(0, 0); stageB(0, 1); stageA(1, 0);

  for (int j = 0; j < NJ; ++j) {
    const int t = 2 * j;           // even tile -> buf0, odd -> buf1
    const bool full = (j < NJ - 1);
    // ph1: compute t / mi0-3 x ni0-1 (reads A0(t), all B(t))
    stageA(t + 1, 1);
    VMC(4);
    BAR(); lda(0, 0); ldb(0); mm(0, 0); LGKM0(); BAR();
    // ph2: t / mi0-3 x ni2-3 (registers only)
    stageB(t + 1, 0);
    BAR(); mm(0, 2); LGKM0(); BAR();
    // ph3: t / mi4-7 x ni0-1 (reads A1(t))
    stageB(t + 1, 1);
    VMC(12);
    BAR(); lda(0, 4); mm(4, 0); LGKM0(); BAR();
    // ph4: t / mi4-7 x ni2-3
    if (full) stageA(t + 2, 0);
    BAR(); mm(4, 2); LGKM0(); BAR();
    // ph5: t+1 / mi0-3 x ni0-1 (reads A0(t+1), all B(t+1))
    if (full) { stageA(t + 2, 1); VMC(4); } else { VMC(0); }
    BAR(); lda(1, 0); ldb(1); mm(0, 0); LGKM0(); BAR();
    // ph6
    if (full) stageB(t + 2, 0);
    BAR(); mm(0, 2); LGKM0(); BAR();
    // ph7 (reads A1(t+1))
    if (full) { stageB(t + 2, 1); VMC(12); } else { VMC(4); }
    BAR(); lda(1, 4); mm(4, 0); LGKM0(); BAR();
    // ph8
    if (full) stageA(t + 3, 0);
    BAR(); mm(4, 2); LGKM0(); BAR();
  }

  // ------------------------------------------------------------------ epilogue
  if (n0 >= 2048) {
    // V block: per-wave transpose in LDS (As region free after final barrier).
    // wave covers head hw = ((n0&1023)>>6) + (w>>1); dd = ni*16+row16;
    // t-local = (mi&3)*4+quad + (mi>>2)*32 with base m0/4 + (w&1)*16.
    const int hw = ((n0 & 1023) >> 6) + (w >> 1);
    unsigned short* tb = &As[0][0][0] + w * 2560;  // 64 dd x 32 tloc, stride 40
    for (int bb = 0; bb < 4; ++bb) {
#pragma unroll
      for (int mi = 0; mi < 8; ++mi)
#pragma unroll
        for (int ni = 0; ni < 4; ++ni) {
          int tloc = (mi & 3) * 4 + quad + (mi >> 2) * 16;
          tb[(ni * 16 + row16) * 40 + tloc] = f2bf(acc[mi][ni][bb]);
        }
      LGKM0();
      unsigned short* vp = Cq + (size_t)(128 + bb * 16 + hw) * PLANE;
#pragma unroll
      for (int it = 0; it < 4; ++it) {
        int dd = it * 16 + (lane >> 2);
        int tl = (lane & 3) * 8;
        s16x8 v = *(const s16x8*)&tb[dd * 40 + tl];
        int tg = (m0 >> 2) + (w & 1) * 16 + (tl >> 4) * 32 + (tl & 15);
        *(s16x8*)(vp + (size_t)dd * T_DIM + tg) = v;
      }
      LGKM0();  // WAR before next bb
    }
  } else {
    // Q/K blocks: [t][d] scatter
    for (int mi = 0; mi < 8; ++mi)
      for (int ni = 0; ni < 4; ++ni)
        for (int r = 0; r < 4; ++r) {
          int m = m0 + (w & 1) * 64 + (mi >> 2) * 128 + (mi & 3) * 16 +
                  quad * 4 + r;
          int n = n0 + (w >> 1) * 64 + ni * 16 + row16;
          int t = m >> 2, bb = m & 3;
          int which = n >> 10, hh = (n >> 6) & 15, dd = n & 63;
          Cq[(size_t)(which * 64 + bb * 16 + hh) * PLANE + (size_t)t * 64 + dd] =
              f2bf(acc[mi][ni][r]);
        }
  }
}

// ---------------------------------------------------------------------------
// gemm128 (m97 structure, swizzled LDS), fp32 output — out-proj.
// ---------------------------------------------------------------------------
__global__ __launch_bounds__(256)
void gemm128(const unsigned short* __restrict__ A,
             const unsigned short* __restrict__ Bw,
             float* __restrict__ Cf, int N, int K) {
  __shared__ __attribute__((aligned(16))) unsigned short As[128 * 64];
  __shared__ __attribute__((aligned(16))) unsigned short Bs[128 * 64];

  const int tid = threadIdx.x, lane = tid & 63, w = tid >> 6;
  const int row16 = lane & 15, quad = lane >> 4;
  const int m0 = blockIdx.y * 128, n0 = blockIdx.x * 128;
  const int wm = (w & 1) * 64, wn = (w >> 1) * 64;
  const int srow = lane >> 3;
  const int jsw = (lane & 7) ^ srow;
  const int sw7 = row16 & 7;

  f32x4 acc[4][4];
  for (int i = 0; i < 4; ++i)
    for (int j = 0; j < 4; ++j) acc[i][j] = (f32x4){0.f, 0.f, 0.f, 0.f};

  for (int k0 = 0; k0 < K; k0 += 64) {
    for (int i = 0; i < 4; ++i) {
      int ia = i * 4 + w;
      int r = ia * 8 + srow;
      gl2lds16(A  + (size_t)(m0 + r) * K + k0 + jsw * 8, &As[ia * 512]);
      gl2lds16(Bw + (size_t)(n0 + r) * K + k0 + jsw * 8, &Bs[ia * 512]);
    }
    __syncthreads();
    for (int kk = 0; kk < 2; ++kk) {
      s16x8 af[4], bfr[4];
      for (int mi = 0; mi < 4; ++mi)
        af[mi] = *(const s16x8*)&As[(wm + mi * 16 + row16) * 64 +
                                    (((kk * 4 + quad) ^ sw7) * 8)];
      for (int ni = 0; ni < 4; ++ni)
        bfr[ni] = *(const s16x8*)&Bs[(wn + ni * 16 + row16) * 64 +
                                     (((kk * 4 + quad) ^ sw7) * 8)];
      for (int mi = 0; mi < 4; ++mi)
        for (int ni = 0; ni < 4; ++ni)
          acc[mi][ni] = mfma16(af[mi], bfr[ni], acc[mi][ni]);
    }
    __syncthreads();
  }

  for (int mi = 0; mi < 4; ++mi)
    for (int ni = 0; ni < 4; ++ni)
      for (int r = 0; r < 4; ++r) {
        int m = m0 + wm + mi * 16 + quad * 4 + r;
        int n = n0 + wn + ni * 16 + row16;
        Cf[(size_t)m * N + n] = acc[mi][ni][r];
      }
}

// ---------------------------------------------------------------------------
// Flash attention (round-13 version). grid = (64, 8), 512 threads (8 waves).
// ---------------------------------------------------------------------------
__global__ __launch_bounds__(512, 4)
void attn_fwd(const unsigned short* __restrict__ qkv,
              unsigned short* __restrict__ ctx) {
  __shared__ __attribute__((aligned(16))) unsigned short Ks[2][4096];
  __shared__ __attribute__((aligned(16))) unsigned short Vs[2][4096];
  __shared__ __attribute__((aligned(16))) unsigned short Ps[8][1024];

  const int tid = threadIdx.x, lane = tid & 63, w = tid >> 6;  // w 0..7
  const int row16 = lane & 15, quad = lane >> 4;
  const int bh = blockIdx.x;     // 0..63
  const int p  = blockIdx.y;     // 0..7
  const int b = bh >> 4, h = bh & 15;

  const unsigned short* Qg = qkv + (size_t)bh * PLANE;          // [t][d]
  const unsigned short* Kg = qkv + (size_t)(64 + bh) * PLANE;   // [t][d]
  const unsigned short* Vt = qkv + (size_t)(128 + bh) * PLANE;  // [d][t]

  const int r8 = lane >> 3;
  const int jsw = (lane & 7) ^ r8;
  const int sw7 = row16 & 7;

  auto stage = [&](int c, int buf) {   // 2 DMA issues per wave per call
    int r = w * 8 + r8;                // 8 waves cover all 64 rows
    gl2lds16(Kg + (size_t)(c * 64 + r) * 64 + jsw * 8, &Ks[buf][w * 512]);
    gl2lds16(Vt + (size_t)r * T_DIM + c * 64 + jsw * 8, &Vs[buf][w * 512]);
  };

  for (int half = 0; half < 2; ++half) {
    const int qt = half ? p : (15 - p);
    const int q0w = qt * 128 + w * 16;
    const int cmax = 2 * qt + 1;           // >= 1 always
    const int dc = 2 * qt + (w >> 2);

    s16x8 qb[2];
    for (int s = 0; s < 2; ++s)
      qb[s] = *(const s16x8*)(Qg + (size_t)(q0w + row16) * 64 + s * 32 +
                              quad * 8);

    f32x4 O[4];
    for (int md = 0; md < 4; ++md) O[md] = (f32x4){0.f, 0.f, 0.f, 0.f};
    float lp = 0.f;

    // 2-deep prologue (final end-of-iter barrier of prev half cleared WAR)
    stage(0, 0);
    stage(1, 1);

    for (int c = 0; c <= cmax; ++c) {
      const int buf = c & 1;
      // Counted wait: own chunk c landed; chunk c+1 stays in flight across
      // the barrier (T4 — drain to 0 only on the final iter).
      if (c < cmax) VMC(2);
      else          VMC(0);
      BAR();  // all waves' chunk c landed

      if (c <= dc) {
        f32x4 S[4];
        for (int nt = 0; nt < 4; ++nt) S[nt] = (f32x4){0.f, 0.f, 0.f, 0.f};
        __builtin_amdgcn_s_setprio(1);
        for (int nt = 0; nt < 4; ++nt)
          for (int s = 0; s < 2; ++s) {
            s16x8 ka = *(const s16x8*)&Ks[buf][(nt * 16 + row16) * 64 +
                                              (((s * 4 + quad) ^ sw7) * 8)];
            S[nt] = mfma16(ka, qb[s], S[nt]);
          }
        __builtin_amdgcn_s_setprio(0);

        // softmax numerator + pack into Ps; diag path carries the causal mask
        const int qg = q0w + row16;
        auto softmax_store = [&](bool diagm) {
          for (int nt = 0; nt < 4; ++nt) {
            float pv[4];
            for (int r = 0; r < 4; ++r) {
              pv[r] = __builtin_amdgcn_exp2f(S[nt][r]);
              if (diagm && (c * 64 + nt * 16 + quad * 4 + r) > qg) pv[r] = 0.f;
              lp += pv[r];
            }
            int pos = (nt * 2 + (quad >> 1)) ^ sw7;
            *(uint2*)&Ps[w][row16 * 64 + pos * 8 + (quad & 1) * 4] =
                make_uint2(packbf(pv[0], pv[1]), packbf(pv[2], pv[3]));
          }
        };
        if (c == dc) softmax_store(true); else softmax_store(false);
        LGKM0();  // Ps is per-wave

        __builtin_amdgcn_s_setprio(1);
        for (int sk = 0; sk < 2; ++sk) {
          s16x8 pb = *(const s16x8*)&Ps[w][row16 * 64 +
                                          (((sk * 4 + quad) ^ sw7) * 8)];
          for (int md = 0; md < 4; ++md) {
            s16x8 va = *(const s16x8*)&Vs[buf][(md * 16 + row16) * 64 +
                                              (((sk * 4 + quad) ^ sw7) * 8)];
            O[md] = mfma16(va, pb, O[md]);
          }
        }
        __builtin_amdgcn_s_setprio(0);
      }

      BAR();  // all waves done reading buf -> WAR clear
      if (c + 2 <= cmax) stage(c + 2, buf);
    }

    {
      float s = lp;
      s += __shfl_xor(s, 16);
      s += __shfl_xor(s, 32);
      float inv = 1.f / s;
      const int t = q0w + row16;
      for (int md = 0; md < 4; ++md) {
        unsigned lo = packbf(O[md][0] * inv, O[md][1] * inv);
        unsigned hi = packbf(O[md][2] * inv, O[md][3] * inv);
        *(uint2*)&ctx[((size_t)t * B_DIM + b) * E_DIM + h * 64 + md * 16 +
                      quad * 4] = make_uint2(lo, hi);
      }
    }
  }
}

// ---------------------------------------------------------------------------
extern "C" void kernel_launch(void* const* d_in, const int* in_sizes, int n_in,
                              void* d_out, int out_size, void* d_ws,
                              size_t ws_size, hipStream_t stream) {
  const float* query = (const float*)d_in[0];  // [T,B,E] = [8192,1024]
  const float* win   = (const float*)d_in[1];  // [3072,1024]
  const float* wout  = (const float*)d_in[2];  // [1024,1024]
  float* out = (float*)d_out;

  const size_t qkv_el = (size_t)3 * 64 * PLANE;   // 25,165,824 ushort
  const size_t ctx_el = (size_t)T_DIM * B_DIM * E_DIM;  // 8,388,608 ushort

  unsigned short* qkvb = (unsigned short*)d_ws;
  unsigned short* ctxb = qkvb + qkv_el;
  unsigned short* xb   = ctxb;                   // dies before ctx written
  unsigned short* winb = (unsigned short*)d_out; // d_out scratch until gemm2

  // W_out bf16: fresh ws region after ctx when it fits (enables upfront
  // merged cvt); else reuse qkvb after attn (old path).
  const bool big_ws = ws_size >= (qkv_el + ctx_el + (size_t)E_DIM * E_DIM) * 2;
  unsigned short* woutb = big_ws ? (ctxb + ctx_el) : qkvb;

  // 0.125 (1/sqrt(D)) * log2(e): folded into W_q so attn uses exp2 directly.
  const float QSCALE = 0.18033688011112042f;

  cvt_all<<<big_ws ? 12288 : 11264, 256, 0, stream>>>(
      query, win, wout, xb, winb, woutb, QSCALE, big_ws ? 1 : 0);
  gemm256<<<dim3(3072 / 256, 8192 / 256), 512, 0, stream>>>(xb, winb, qkvb,
                                                            1024);
  attn_fwd<<<dim3(64, 8), 512, 0, stream>>>(qkvb, ctxb);
  if (!big_ws)
    cvt_bf16<<<1024, 256, 0, stream>>>(wout, woutb, (1024 * 1024) / 4);
  gemm128<<<dim3(8, 64), 256, 0, stream>>>(ctxb, woutb, out, 1024, 1024);
}

// Round 7
// 231.948 us; speedup vs baseline: 1.0139x; 1.0139x over previous
//
#include <hip/hip_runtime.h>

// ---------------------------------------------------------------------------
// SelfMultiheadAttn fwd: T=2048, B=4, E=1024, H=16, D=64, causal.
// Round 15: gemm256 8-phase schedule with CORRECTED prefetch lead.
// Round-14 flaw (measured flat 72us, MfmaUtil 27.7): tile t+1 was staged at
// ph1-3 and consumed at ph5-7 of the SAME iter -> 2-phase lead, every ph1/ph5
// vmcnt stalled on a ~2-phase-old DMA. New slots stage each half a full
// K-tile ahead (lead 5-7 phases):
//   ph1:A1(t+1)  ph2:B0(t+2)  ph3:B1(t+2)  ph4:A0(t+2)
//   ph5:A1(t+2)  ph6:B0(t+3)  ph7:B1(t+3)  ph8:A0(t+3)
// FIFO ledger (2 loads/stage/wave): ph1 VMC(8) (forces t's A0/B0/B1 AND A1
// -> ph3 waitless), ph5 VMC(10) (forces A0/B0/B1(t+1)), ph7 VMC(12) (forces
// A1(t+1)); last iter: ph5 VMC(2), ph7 VMC(0). Prologue stages
// A0(0),B0(0),B1(0),A1(0),B0(1),B1(1),A0(1) so iter-0 ph1's VMC(8) drops
// exactly tile 0. WAR: every overwrite is >=1 phase after the last read of
// that half (trailing LGKM0+BAR per phase).
// Kept: attn round-13 (8-wave, counted vmcnt, XCD-paired grid), gemm128,
// merged cvt, exp2-folded W_q, V-transpose epilogue.
// ---------------------------------------------------------------------------

typedef float  f32x4  __attribute__((ext_vector_type(4)));
typedef short  s16x8  __attribute__((ext_vector_type(8)));
typedef __bf16 bf16x8 __attribute__((ext_vector_type(8)));

#define T_DIM 2048
#define B_DIM 4
#define E_DIM 1024
#define PLANE (T_DIM * 64)   // elements per (which,b,h) plane

#define VMC(N) asm volatile("s_waitcnt vmcnt(" #N ")" ::: "memory")
#define LGKM0() asm volatile("s_waitcnt lgkmcnt(0)" ::: "memory")
#define BAR() __builtin_amdgcn_s_barrier()

__device__ inline unsigned short f2bf(float f) {
  return (unsigned short)((__builtin_bit_cast(unsigned int, f) + 0x8000u) >> 16);
}

__device__ inline f32x4 mfma16(s16x8 a, s16x8 b, f32x4 c) {
  return __builtin_amdgcn_mfma_f32_16x16x32_bf16(
      __builtin_bit_cast(bf16x8, a), __builtin_bit_cast(bf16x8, b), c, 0, 0, 0);
}

__device__ inline void gl2lds16(const unsigned short* g, unsigned short* l) {
  __builtin_amdgcn_global_load_lds(
      (__attribute__((address_space(1))) unsigned int*)g,
      (__attribute__((address_space(3))) unsigned int*)l, 16, 0, 0);
}

// pack hi16(a) | hi16(b)<<16  (bf16 truncation) in one v_perm
__device__ inline unsigned packbf(float a, float b) {
  return __builtin_amdgcn_perm(__builtin_bit_cast(unsigned, b),
                               __builtin_bit_cast(unsigned, a), 0x07060302u);
}

// ---------------------------------------------------------------------------
// Merged input conversion: blocks [0,8192) query -> xb; [8192,11264) W_in ->
// winb (first E*E/4 float4s carry the Q scale); [11264,12288) W_out -> wob
// (skipped when do_wout==0; fallback path converts W_out after attn).
// ---------------------------------------------------------------------------
__global__ __launch_bounds__(256)
void cvt_all(const float* __restrict__ q, const float* __restrict__ wi,
             const float* __restrict__ wo, unsigned short* __restrict__ xb,
             unsigned short* __restrict__ wib, unsigned short* __restrict__ wob,
             float qs, int do_wout) {
  int blk = blockIdx.x;
  const float* src;
  unsigned short* dst;
  int i;
  float sc = 1.0f;
  if (blk < 8192) {
    src = q; dst = xb; i = blk * 256 + threadIdx.x;
  } else if (blk < 11264) {
    src = wi; dst = wib; i = (blk - 8192) * 256 + threadIdx.x;
    if (i < (E_DIM * E_DIM / 4)) sc = qs;
  } else {
    if (!do_wout) return;
    src = wo; dst = wob; i = (blk - 11264) * 256 + threadIdx.x;
  }
  float4 v = ((const float4*)src)[i];
  ushort4 o;
  o.x = f2bf(v.x * sc); o.y = f2bf(v.y * sc);
  o.z = f2bf(v.z * sc); o.w = f2bf(v.w * sc);
  ((ushort4*)dst)[i] = o;
}

__global__ __launch_bounds__(256)
void cvt_bf16(const float* __restrict__ in, unsigned short* __restrict__ out,
              int n4) {
  int i = blockIdx.x * 256 + threadIdx.x;
  if (i >= n4) return;
  float4 v = ((const float4*)in)[i];
  ushort4 o;
  o.x = f2bf(v.x); o.y = f2bf(v.y); o.z = f2bf(v.z); o.w = f2bf(v.w);
  ((ushort4*)out)[i] = o;
}

// ---------------------------------------------------------------------------
// gemm256: C[m,n]=sum_k A[m,k]*B[n,k]; 256x256 tile, 8-phase counted-vmcnt
// schedule (full-K-tile prefetch lead). Epilogue -> qkv scatter; V block via
// per-wave LDS transpose.
// ---------------------------------------------------------------------------
__global__ __launch_bounds__(512, 2)
void gemm256(const unsigned short* __restrict__ A,
             const unsigned short* __restrict__ Bw,
             unsigned short* __restrict__ Cq, int K) {
  // [buf][half][128 rows x 64 cols] each; A + B = 128 KB total
  __shared__ __attribute__((aligned(16))) unsigned short As[2][2][8192];
  __shared__ __attribute__((aligned(16))) unsigned short Bs[2][2][8192];

  const int tid = threadIdx.x, lane = tid & 63, w = tid >> 6;  // w 0..7
  const int row16 = lane & 15, quad = lane >> 4;
  const int m0 = blockIdx.y * 256, n0 = blockIdx.x * 256;
  const int r8 = lane >> 3;
  const int jsw = (lane & 7) ^ r8;   // staging source swizzle
  const int sw7 = row16 & 7;         // read-side swizzle key

  f32x4 acc[8][4];
#pragma unroll
  for (int i = 0; i < 8; ++i)
#pragma unroll
    for (int j = 0; j < 4; ++j) acc[i][j] = (f32x4){0.f, 0.f, 0.f, 0.f};

  auto stageA = [&](int tile, int half) {
#pragma unroll
    for (int i2 = 0; i2 < 2; ++i2) {
      int ia = w * 2 + i2;  // 0..15
      gl2lds16(A + (size_t)(m0 + half * 128 + ia * 8 + r8) * K + tile * 64 +
                   jsw * 8,
               &As[tile & 1][half][ia * 512]);
    }
  };
  auto stageB = [&](int tile, int half) {
#pragma unroll
    for (int i2 = 0; i2 < 2; ++i2) {
      int ia = w * 2 + i2;
      gl2lds16(Bw + (size_t)(n0 + half * 128 + ia * 8 + r8) * K + tile * 64 +
                    jsw * 8,
               &Bs[tile & 1][half][ia * 512]);
    }
  };

  s16x8 a[4][2], bq[4][2];

  auto lda = [&](int buf, int mlo) {  // mlo literal at call sites (0 or 4)
#pragma unroll
    for (int mi2 = 0; mi2 < 4; ++mi2)
#pragma unroll
      for (int s = 0; s < 2; ++s)
        a[mi2][s] = *(const s16x8*)&As[buf][mlo >> 2]
            [((w & 1) * 64 + mi2 * 16 + row16) * 64 +
             (((s * 4 + quad) ^ sw7) * 8)];
  };
  auto ldb = [&](int buf) {  // all 4 n-frags, both ksubs, register-held
#pragma unroll
    for (int ni = 0; ni < 4; ++ni)
#pragma unroll
      for (int s = 0; s < 2; ++s)
        bq[ni][s] = *(const s16x8*)&Bs[buf][w >> 2]
            [(((w >> 1) & 1) * 64 + ni * 16 + row16) * 64 +
             (((s * 4 + quad) ^ sw7) * 8)];
  };
  auto mm = [&](int mlo, int nlo) {  // 16 MFMA
    __builtin_amdgcn_s_setprio(1);
#pragma unroll
    for (int mi2 = 0; mi2 < 4; ++mi2)
#pragma unroll
      for (int ni2 = 0; ni2 < 2; ++ni2)
#pragma unroll
        for (int s = 0; s < 2; ++s)
          acc[mlo + mi2][nlo + ni2] =
              mfma16(a[mi2][s], bq[nlo + ni2][s], acc[mlo + mi2][nlo + ni2]);
    __builtin_amdgcn_s_setprio(0);
  };

  const int NJ = K / 128;  // 8 iters of 2 K-tiles

  // Prologue: tile 0 fully + B0/B1/A0 of tile 1, ordered so that iter-0
  // ph1's VMC(8) drops exactly tile 0's four halves.
  stageA(0, 0); stageB(0, 0); stageB(0, 1); stageA(0, 1);
  stageB(1, 0); stageB(1, 1); stageA(1, 0);

  for (int j = 0; j < NJ; ++j) {
    const int t = 2 * j;           // even tile -> buf0, odd -> buf1
    const bool full = (j < NJ - 1);
    // ph1: reads A0(t) + all B(t); forces A1(t) too (ph3 waitless)
    stageA(t + 1, 1);
    VMC(8);
    BAR(); lda(0, 0); ldb(0); mm(0, 0); LGKM0(); BAR();
    // ph2 (regs only)
    if (full) stageB(t + 2, 0);
    BAR(); mm(0, 2); LGKM0(); BAR();
    // ph3: reads A1(t) (already forced by ph1's VMC(8))
    if (full) stageB(t + 2, 1);
    BAR(); lda(0, 4); mm(4, 0); LGKM0(); BAR();
    // ph4 (regs only)
    if (full) stageA(t + 2, 0);
    BAR(); mm(4, 2); LGKM0(); BAR();
    // ph5: reads A0(t+1) + all B(t+1)
    if (full) { stageA(t + 2, 1); VMC(10); } else { VMC(2); }
    BAR(); lda(1, 0); ldb(1); mm(0, 0); LGKM0(); BAR();
    // ph6 (regs only)
    if (full) stageB(t + 3, 0);
    BAR(); mm(0, 2); LGKM0(); BAR();
    // ph7: reads A1(t+1)
    if (full) { stageB(t + 3, 1); VMC(12); } else { VMC(0); }
    BAR(); lda(1, 4); mm(4, 0); LGKM0(); BAR();
    // ph8 (regs only)
    if (full) stageA(t + 3, 0);
    BAR(); mm(4, 2); LGKM0(); BAR();
  }

  // ------------------------------------------------------------------ epilogue
  if (n0 >= 2048) {
    // V block: per-wave transpose in LDS (As region free after final barrier).
    // wave covers head hw = ((n0&1023)>>6) + (w>>1); dd = ni*16+row16;
    // t-local = (mi&3)*4+quad + (mi>>2)*16 within wave's 32-t slab.
    const int hw = ((n0 & 1023) >> 6) + (w >> 1);
    unsigned short* tb = &As[0][0][0] + w * 2560;  // 64 dd x 32 tloc, stride 40
    for (int bb = 0; bb < 4; ++bb) {
#pragma unroll
      for (int mi = 0; mi < 8; ++mi)
#pragma unroll
        for (int ni = 0; ni < 4; ++ni) {
          int tloc = (mi & 3) * 4 + quad + (mi >> 2) * 16;
          tb[(ni * 16 + row16) * 40 + tloc] = f2bf(acc[mi][ni][bb]);
        }
      LGKM0();
      unsigned short* vp = Cq + (size_t)(128 + bb * 16 + hw) * PLANE;
#pragma unroll
      for (int it = 0; it < 4; ++it) {
        int dd = it * 16 + (lane >> 2);
        int tl = (lane & 3) * 8;
        s16x8 v = *(const s16x8*)&tb[dd * 40 + tl];
        int tg = (m0 >> 2) + (w & 1) * 16 + (tl >> 4) * 32 + (tl & 15);
        *(s16x8*)(vp + (size_t)dd * T_DIM + tg) = v;
      }
      LGKM0();  // WAR before next bb
    }
  } else {
    // Q/K blocks: [t][d] scatter
    for (int mi = 0; mi < 8; ++mi)
      for (int ni = 0; ni < 4; ++ni)
        for (int r = 0; r < 4; ++r) {
          int m = m0 + (w & 1) * 64 + (mi >> 2) * 128 + (mi & 3) * 16 +
                  quad * 4 + r;
          int n = n0 + (w >> 1) * 64 + ni * 16 + row16;
          int t = m >> 2, bb = m & 3;
          int which = n >> 10, hh = (n >> 6) & 15, dd = n & 63;
          Cq[(size_t)(which * 64 + bb * 16 + hh) * PLANE + (size_t)t * 64 + dd] =
              f2bf(acc[mi][ni][r]);
        }
  }
}

// ---------------------------------------------------------------------------
// gemm128 (m97 structure, swizzled LDS), fp32 output — out-proj.
// ---------------------------------------------------------------------------
__global__ __launch_bounds__(256)
void gemm128(const unsigned short* __restrict__ A,
             const unsigned short* __restrict__ Bw,
             float* __restrict__ Cf, int N, int K) {
  __shared__ __attribute__((aligned(16))) unsigned short As[128 * 64];
  __shared__ __attribute__((aligned(16))) unsigned short Bs[128 * 64];

  const int tid = threadIdx.x, lane = tid & 63, w = tid >> 6;
  const int row16 = lane & 15, quad = lane >> 4;
  const int m0 = blockIdx.y * 128, n0 = blockIdx.x * 128;
  const int wm = (w & 1) * 64, wn = (w >> 1) * 64;
  const int srow = lane >> 3;
  const int jsw = (lane & 7) ^ srow;
  const int sw7 = row16 & 7;

  f32x4 acc[4][4];
  for (int i = 0; i < 4; ++i)
    for (int j = 0; j < 4; ++j) acc[i][j] = (f32x4){0.f, 0.f, 0.f, 0.f};

  for (int k0 = 0; k0 < K; k0 += 64) {
    for (int i = 0; i < 4; ++i) {
      int ia = i * 4 + w;
      int r = ia * 8 + srow;
      gl2lds16(A  + (size_t)(m0 + r) * K + k0 + jsw * 8, &As[ia * 512]);
      gl2lds16(Bw + (size_t)(n0 + r) * K + k0 + jsw * 8, &Bs[ia * 512]);
    }
    __syncthreads();
    for (int kk = 0; kk < 2; ++kk) {
      s16x8 af[4], bfr[4];
      for (int mi = 0; mi < 4; ++mi)
        af[mi] = *(const s16x8*)&As[(wm + mi * 16 + row16) * 64 +
                                    (((kk * 4 + quad) ^ sw7) * 8)];
      for (int ni = 0; ni < 4; ++ni)
        bfr[ni] = *(const s16x8*)&Bs[(wn + ni * 16 + row16) * 64 +
                                     (((kk * 4 + quad) ^ sw7) * 8)];
      for (int mi = 0; mi < 4; ++mi)
        for (int ni = 0; ni < 4; ++ni)
          acc[mi][ni] = mfma16(af[mi], bfr[ni], acc[mi][ni]);
    }
    __syncthreads();
  }

  for (int mi = 0; mi < 4; ++mi)
    for (int ni = 0; ni < 4; ++ni)
      for (int r = 0; r < 4; ++r) {
        int m = m0 + wm + mi * 16 + quad * 4 + r;
        int n = n0 + wn + ni * 16 + row16;
        Cf[(size_t)m * N + n] = acc[mi][ni][r];
      }
}

// ---------------------------------------------------------------------------
// Flash attention (round-13 version). grid = (64, 8), 512 threads (8 waves).
// ---------------------------------------------------------------------------
__global__ __launch_bounds__(512, 4)
void attn_fwd(const unsigned short* __restrict__ qkv,
              unsigned short* __restrict__ ctx) {
  __shared__ __attribute__((aligned(16))) unsigned short Ks[2][4096];
  __shared__ __attribute__((aligned(16))) unsigned short Vs[2][4096];
  __shared__ __attribute__((aligned(16))) unsigned short Ps[8][1024];

  const int tid = threadIdx.x, lane = tid & 63, w = tid >> 6;  // w 0..7
  const int row16 = lane & 15, quad = lane >> 4;
  const int bh = blockIdx.x;     // 0..63
  const int p  = blockIdx.y;     // 0..7
  const int b = bh >> 4, h = bh & 15;

  const unsigned short* Qg = qkv + (size_t)bh * PLANE;          // [t][d]
  const unsigned short* Kg = qkv + (size_t)(64 + bh) * PLANE;   // [t][d]
  const unsigned short* Vt = qkv + (size_t)(128 + bh) * PLANE;  // [d][t]

  const int r8 = lane >> 3;
  const int jsw = (lane & 7) ^ r8;
  const int sw7 = row16 & 7;

  auto stage = [&](int c, int buf) {   // 2 DMA issues per wave per call
    int r = w * 8 + r8;                // 8 waves cover all 64 rows
    gl2lds16(Kg + (size_t)(c * 64 + r) * 64 + jsw * 8, &Ks[buf][w * 512]);
    gl2lds16(Vt + (size_t)r * T_DIM + c * 64 + jsw * 8, &Vs[buf][w * 512]);
  };

  for (int half = 0; half < 2; ++half) {
    const int qt = half ? p : (15 - p);
    const int q0w = qt * 128 + w * 16;
    const int cmax = 2 * qt + 1;           // >= 1 always
    const int dc = 2 * qt + (w >> 2);

    s16x8 qb[2];
    for (int s = 0; s < 2; ++s)
      qb[s] = *(const s16x8*)(Qg + (size_t)(q0w + row16) * 64 + s * 32 +
                              quad * 8);

    f32x4 O[4];
    for (int md = 0; md < 4; ++md) O[md] = (f32x4){0.f, 0.f, 0.f, 0.f};
    float lp = 0.f;

    // 2-deep prologue (final end-of-iter barrier of prev half cleared WAR)
    stage(0, 0);
    stage(1, 1);

    for (int c = 0; c <= cmax; ++c) {
      const int buf = c & 1;
      // Counted wait: own chunk c landed; chunk c+1 stays in flight across
      // the barrier (T4 — drain to 0 only on the final iter).
      if (c < cmax) VMC(2);
      else          VMC(0);
      BAR();  // all waves' chunk c landed

      if (c <= dc) {
        f32x4 S[4];
        for (int nt = 0; nt < 4; ++nt) S[nt] = (f32x4){0.f, 0.f, 0.f, 0.f};
        __builtin_amdgcn_s_setprio(1);
        for (int nt = 0; nt < 4; ++nt)
          for (int s = 0; s < 2; ++s) {
            s16x8 ka = *(const s16x8*)&Ks[buf][(nt * 16 + row16) * 64 +
                                              (((s * 4 + quad) ^ sw7) * 8)];
            S[nt] = mfma16(ka, qb[s], S[nt]);
          }
        __builtin_amdgcn_s_setprio(0);

        // softmax numerator + pack into Ps; diag path carries the causal mask
        const int qg = q0w + row16;
        auto softmax_store = [&](bool diagm) {
          for (int nt = 0; nt < 4; ++nt) {
            float pv[4];
            for (int r = 0; r < 4; ++r) {
              pv[r] = __builtin_amdgcn_exp2f(S[nt][r]);
              if (diagm && (c * 64 + nt * 16 + quad * 4 + r) > qg) pv[r] = 0.f;
              lp += pv[r];
            }
            int pos = (nt * 2 + (quad >> 1)) ^ sw7;
            *(uint2*)&Ps[w][row16 * 64 + pos * 8 + (quad & 1) * 4] =
                make_uint2(packbf(pv[0], pv[1]), packbf(pv[2], pv[3]));
          }
        };
        if (c == dc) softmax_store(true); else softmax_store(false);
        LGKM0();  // Ps is per-wave

        __builtin_amdgcn_s_setprio(1);
        for (int sk = 0; sk < 2; ++sk) {
          s16x8 pb = *(const s16x8*)&Ps[w][row16 * 64 +
                                          (((sk * 4 + quad) ^ sw7) * 8)];
          for (int md = 0; md < 4; ++md) {
            s16x8 va = *(const s16x8*)&Vs[buf][(md * 16 + row16) * 64 +
                                              (((sk * 4 + quad) ^ sw7) * 8)];
            O[md] = mfma16(va, pb, O[md]);
          }
        }
        __builtin_amdgcn_s_setprio(0);
      }

      BAR();  // all waves done reading buf -> WAR clear
      if (c + 2 <= cmax) stage(c + 2, buf);
    }

    {
      float s = lp;
      s += __shfl_xor(s, 16);
      s += __shfl_xor(s, 32);
      float inv = 1.f / s;
      const int t = q0w + row16;
      for (int md = 0; md < 4; ++md) {
        unsigned lo = packbf(O[md][0] * inv, O[md][1] * inv);
        unsigned hi = packbf(O[md][2] * inv, O[md][3] * inv);
        *(uint2*)&ctx[((size_t)t * B_DIM + b) * E_DIM + h * 64 + md * 16 +
                      quad * 4] = make_uint2(lo, hi);
      }
    }
  }
}

// ---------------------------------------------------------------------------
extern "C" void kernel_launch(void* const* d_in, const int* in_sizes, int n_in,
                              void* d_out, int out_size, void* d_ws,
                              size_t ws_size, hipStream_t stream) {
  const float* query = (const float*)d_in[0];  // [T,B,E] = [8192,1024]
  const float* win   = (const float*)d_in[1];  // [3072,1024]
  const float* wout  = (const float*)d_in[2];  // [1024,1024]
  float* out = (float*)d_out;

  const size_t qkv_el = (size_t)3 * 64 * PLANE;   // 25,165,824 ushort
  const size_t ctx_el = (size_t)T_DIM * B_DIM * E_DIM;  // 8,388,608 ushort

  unsigned short* qkvb = (unsigned short*)d_ws;
  unsigned short* ctxb = qkvb + qkv_el;
  unsigned short* xb   = ctxb;                   // dies before ctx written
  unsigned short* winb = (unsigned short*)d_out; // d_out scratch until gemm2

  // W_out bf16: fresh ws region after ctx when it fits (enables upfront
  // merged cvt); else reuse qkvb after attn (old path).
  const bool big_ws = ws_size >= (qkv_el + ctx_el + (size_t)E_DIM * E_DIM) * 2;
  unsigned short* woutb = big_ws ? (ctxb + ctx_el) : qkvb;

  // 0.125 (1/sqrt(D)) * log2(e): folded into W_q so attn uses exp2 directly.
  const float QSCALE = 0.18033688011112042f;

  cvt_all<<<big_ws ? 12288 : 11264, 256, 0, stream>>>(
      query, win, wout, xb, winb, woutb, QSCALE, big_ws ? 1 : 0);
  gemm256<<<dim3(3072 / 256, 8192 / 256), 512, 0, stream>>>(xb, winb, qkvb,
                                                            1024);
  attn_fwd<<<dim3(64, 8), 512, 0, stream>>>(qkvb, ctxb);
  if (!big_ws)
    cvt_bf16<<<1024, 256, 0, stream>>>(wout, woutb, (1024 * 1024) / 4);
  gemm128<<<dim3(8, 64), 256, 0, stream>>>(ctxb, woutb, out, 1024, 1024);
}